// Round 5
// baseline (60449.213 us; speedup 1.0000x reference)
//
#include <hip/hip_runtime.h>
#include <hip/hip_bf16.h>
#include <cstdint>
#include <cstddef>

#define TSEQ 2048
#define BB   32
#define DD   256
#define UU   512
#define NCOL 1536
#define GB   32      // blocks per group
#define RING 8       // h1 ring depth (timesteps)

static __device__ __forceinline__ float aload(const float* p) {
    return __int_as_float(__hip_atomic_load((const int*)p, __ATOMIC_RELAXED,
                                            __HIP_MEMORY_SCOPE_AGENT));
}
static __device__ __forceinline__ void astore(float* p, float v) {
    __hip_atomic_store((int*)p, __float_as_int(v), __ATOMIC_RELAXED,
                       __HIP_MEMORY_SCOPE_AGENT);
}
static __device__ __forceinline__ unsigned f2bfu(float f) {
    __hip_bfloat16 b = __float2bfloat16(f);
    unsigned short s;
    __builtin_memcpy(&s, &b, 2);
    return (unsigned)s;
}
static __device__ __forceinline__ float bflo(unsigned u) { return __uint_as_float(u << 16); }
static __device__ __forceinline__ float bfhi(unsigned u) { return __uint_as_float(u & 0xffff0000u); }
static __device__ __forceinline__ int swz512(int k) { return k ^ (((k >> 6) & 7) << 2); }

// ---------------------------------------------------------------------------
// fp32 GEMM for xp1 = x@k1 + b_in  (proven R3 kernel)
// ---------------------------------------------------------------------------
__global__ __launch_bounds__(256)
void gemm_bias(const float* __restrict__ A, const float* __restrict__ W,
               const float* __restrict__ bias, float* __restrict__ C,
               int M, int N, int K)
{
    __shared__ float As[16][68];
    __shared__ float Bs[16][64];

    const int tid = threadIdx.x;
    const int tx = tid & 15, ty = tid >> 4;
    const int m0 = blockIdx.y * 64, n0 = blockIdx.x * 64;

    float acc[4][4] = {};

    for (int k0 = 0; k0 < K; k0 += 16) {
        {
            int r  = tid >> 2;
            int kq = (tid & 3) * 4;
            float4 av = *(const float4*)&A[(size_t)(m0 + r) * K + k0 + kq];
            As[kq + 0][r] = av.x;
            As[kq + 1][r] = av.y;
            As[kq + 2][r] = av.z;
            As[kq + 3][r] = av.w;
        }
        {
            int kk = tid >> 4;
            int n  = (tid & 15) * 4;
            *(float4*)&Bs[kk][n] = *(const float4*)&W[(size_t)(k0 + kk) * N + n0 + n];
        }
        __syncthreads();

        #pragma unroll
        for (int kk = 0; kk < 16; ++kk) {
            float av0 = As[kk][ty * 4 + 0];
            float av1 = As[kk][ty * 4 + 1];
            float av2 = As[kk][ty * 4 + 2];
            float av3 = As[kk][ty * 4 + 3];
            float4 bv = *(const float4*)&Bs[kk][tx * 4];
            acc[0][0] = fmaf(av0, bv.x, acc[0][0]);
            acc[0][1] = fmaf(av0, bv.y, acc[0][1]);
            acc[0][2] = fmaf(av0, bv.z, acc[0][2]);
            acc[0][3] = fmaf(av0, bv.w, acc[0][3]);
            acc[1][0] = fmaf(av1, bv.x, acc[1][0]);
            acc[1][1] = fmaf(av1, bv.y, acc[1][1]);
            acc[1][2] = fmaf(av1, bv.z, acc[1][2]);
            acc[1][3] = fmaf(av1, bv.w, acc[1][3]);
            acc[2][0] = fmaf(av2, bv.x, acc[2][0]);
            acc[2][1] = fmaf(av2, bv.y, acc[2][1]);
            acc[2][2] = fmaf(av2, bv.z, acc[2][2]);
            acc[2][3] = fmaf(av2, bv.w, acc[2][3]);
            acc[3][0] = fmaf(av3, bv.x, acc[3][0]);
            acc[3][1] = fmaf(av3, bv.y, acc[3][1]);
            acc[3][2] = fmaf(av3, bv.z, acc[3][2]);
            acc[3][3] = fmaf(av3, bv.w, acc[3][3]);
        }
        __syncthreads();
    }

    float4 bb = *(const float4*)&bias[n0 + tx * 4];
    #pragma unroll
    for (int i = 0; i < 4; ++i) {
        float4 v;
        v.x = acc[i][0] + bb.x;
        v.y = acc[i][1] + bb.y;
        v.z = acc[i][2] + bb.z;
        v.w = acc[i][3] + bb.w;
        *(float4*)&C[(size_t)(m0 + ty * 4 + i) * N + n0 + tx * 4] = v;
    }
}

// ---------------------------------------------------------------------------
// Fused persistent 2-layer GRU. 512 blocks x 512 threads, 2 blocks/CU
// guaranteed by __launch_bounds__(512,4).
//  A (0..255):   layer-1 scan; xp1 read from precomputed buffer; rk1 bf16 in
//                32 packed VGPRs; publishes h1 to an 8-deep ring.
//  C (256..511): layer-2 scan; computes xp2 = h1@k2 on the fly; rk2/k2 bf16
//                in 64 packed VGPRs; writes out2/state2.
// All cross-block state via RELAXED AGENT atomics (coherence point, no
// fences); __syncthreads() drains vmcnt before each flag post.
// Deps: A@t <- {A-grp@t-1, C-grp@t-7}; C@t <- {C-grp@t-1, A-grp@t}. Acyclic.
// ---------------------------------------------------------------------------
__global__ __launch_bounds__(512, 4)
void gru_fused(const float* __restrict__ xp1,  const float* __restrict__ h0,
               const float* __restrict__ rk1,  const float* __restrict__ b1,
               const float* __restrict__ k2,   const float* __restrict__ rk2,
               const float* __restrict__ b2,
               float* h1ring,                 // [RING][BB][UU]
               float* hp2,                    // [2][BB][UU]
               int* aflags, int* cflags,      // [256] each, zeroed
               float* __restrict__ out2, float* __restrict__ state1,
               float* __restrict__ state2)
{
    __shared__ float hl1[4][512];
    __shared__ float hl2[4][512];
    __shared__ float innR[48][4];
    __shared__ float innX[48][4];
    __shared__ float xp[2][192];

    const int tid  = threadIdx.x;
    const int bid  = blockIdx.x;
    const bool isA = (bid < 256);
    const int lb   = isA ? bid : (bid - 256);
    const int g    = lb & 7,  slot = lb >> 3;
    const int u0   = slot * 16, b0 = g * 4;
    const int c    = tid >> 3, j = tid & 7;
    const int jsw  = j << 2;
    const int col  = (c < 48) ? ((c >> 4) * UU + u0 + (c & 15)) : 0;

    if (isA) {
        // ================= ROLE A : layer-1 =================
        unsigned wr[32];                       // rk1 slice, bf16-packed
        if (c < 48) {
            const float* rb = rk1 + (size_t)(j * 64) * NCOL + col;
            #pragma unroll
            for (int m = 0; m < 32; ++m)
                wr[m] = f2bfu(rb[(size_t)(2 * m) * NCOL])
                      | (f2bfu(rb[(size_t)(2 * m + 1) * NCOL]) << 16);
        }
        float brz = 0, brr = 0, brh = 0;
        if (tid < 64) {
            int iu = tid & 15;
            brz = b1[NCOL + u0 + iu];
            brr = b1[NCOL + UU + u0 + iu];
            brh = b1[NCOL + 2 * UU + u0 + iu];
        }
        if (tid >= 384) {                      // prefill xp[0] (t=0)
            int p = tid - 384;
            {
                int cc = p >> 2, b = p & 3;
                xp[0][p] = xp1[((size_t)(b0 + b) * TSEQ + 0) * NCOL
                               + (cc >> 4) * UU + u0 + (cc & 15)];
            }
            int p2 = p + 128;
            if (p2 < 192) {
                int cc = p2 >> 2, b = p2 & 3;
                xp[0][p2] = xp1[((size_t)(b0 + b) * TSEQ + 0) * NCOL
                                + (cc >> 4) * UU + u0 + (cc & 15)];
            }
        }
        __syncthreads();

        for (int t = 0; t < TSEQ; ++t) {
            if (t > 0) {
                if (tid < 64) {
                    const int* fp = (tid < 32) ? &aflags[g * GB + tid]
                                               : &cflags[g * GB + (tid - 32)];
                    const int thr = (tid < 32) ? t : (t - (RING - 1));
                    while (!__all(__hip_atomic_load(fp, __ATOMIC_RELAXED,
                                  __HIP_MEMORY_SCOPE_AGENT) >= thr)) {}
                }
                __syncthreads();
            }
            {   // stage h1[t-1]
                const float* hs = h1ring + (size_t)((t - 1) & 7) * BB * UU;
                #pragma unroll
                for (int i = 0; i < 4; ++i) {
                    int idx = i * 512 + tid;
                    int row = idx >> 9, k = idx & 511;
                    float v = (t == 0) ? h0[(size_t)(b0 + row) * UU + k]
                                       : aload(&hs[(size_t)(b0 + row) * UU + k]);
                    hl1[row][swz512(k)] = v;
                }
            }
            __syncthreads();

            if (c < 48) {
                float a0 = 0, a1 = 0, a2 = 0, a3 = 0;
                const int kb = j * 64;
                #pragma unroll
                for (int q0 = 0; q0 < 64; q0 += 4) {
                    int p = kb + (q0 ^ jsw);
                    float4 v0 = *(const float4*)&hl1[0][p];
                    float4 v1 = *(const float4*)&hl1[1][p];
                    float4 v2 = *(const float4*)&hl1[2][p];
                    float4 v3 = *(const float4*)&hl1[3][p];
                    unsigned wa = wr[q0 >> 1], wb = wr[(q0 >> 1) + 1];
                    float w0 = bflo(wa), w1 = bfhi(wa), w2 = bflo(wb), w3 = bfhi(wb);
                    a0 = fmaf(w0, v0.x, a0); a1 = fmaf(w0, v1.x, a1);
                    a2 = fmaf(w0, v2.x, a2); a3 = fmaf(w0, v3.x, a3);
                    a0 = fmaf(w1, v0.y, a0); a1 = fmaf(w1, v1.y, a1);
                    a2 = fmaf(w1, v2.y, a2); a3 = fmaf(w1, v3.y, a3);
                    a0 = fmaf(w2, v0.z, a0); a1 = fmaf(w2, v1.z, a1);
                    a2 = fmaf(w2, v2.z, a2); a3 = fmaf(w2, v3.z, a3);
                    a0 = fmaf(w3, v0.w, a0); a1 = fmaf(w3, v1.w, a1);
                    a2 = fmaf(w3, v2.w, a2); a3 = fmaf(w3, v3.w, a3);
                }
                #pragma unroll
                for (int m = 1; m < 8; m <<= 1) {
                    a0 += __shfl_xor(a0, m); a1 += __shfl_xor(a1, m);
                    a2 += __shfl_xor(a2, m); a3 += __shfl_xor(a3, m);
                }
                if (j == 0) {
                    innR[c][0] = a0; innR[c][1] = a1;
                    innR[c][2] = a2; innR[c][3] = a3;
                }
            } else if (tid >= 384 && t + 1 < TSEQ) {   // prefetch xp1[t+1]
                int p = tid - 384, nb = (t + 1) & 1;
                {
                    int cc = p >> 2, b = p & 3;
                    xp[nb][p] = xp1[((size_t)(b0 + b) * TSEQ + (t + 1)) * NCOL
                                    + (cc >> 4) * UU + u0 + (cc & 15)];
                }
                int p2 = p + 128;
                if (p2 < 192) {
                    int cc = p2 >> 2, b = p2 & 3;
                    xp[nb][p2] = xp1[((size_t)(b0 + b) * TSEQ + (t + 1)) * NCOL
                                     + (cc >> 4) * UU + u0 + (cc & 15)];
                }
            }
            __syncthreads();

            if (tid < 64) {
                int bl = tid >> 4, iu = tid & 15, ug = u0 + iu;
                float rz = innR[iu][bl]      + brz;
                float rr = innR[16 + iu][bl] + brr;
                float rh = innR[32 + iu][bl] + brh;
                const float* xv = xp[t & 1];
                float xz = xv[iu * 4 + bl];
                float xr = xv[(16 + iu) * 4 + bl];
                float xh = xv[(32 + iu) * 4 + bl];
                float z  = 1.f / (1.f + expf(-(xz + rz)));
                float r  = 1.f / (1.f + expf(-(xr + rr)));
                float hh = tanhf(xh + r * rh);
                float hold = hl1[bl][swz512(ug)];
                float hnew = z * hold + (1.f - z) * hh;
                astore(h1ring + (size_t)(t & 7) * BB * UU
                              + (size_t)(b0 + bl) * UU + ug, hnew);
                if (t == TSEQ - 1) state1[(size_t)(b0 + bl) * UU + ug] = hnew;
            }
            __syncthreads();   // drains vmcnt: h stores at MALL before flag
            if (tid == 0)
                __hip_atomic_store(&aflags[g * GB + slot], t + 1,
                                   __ATOMIC_RELAXED, __HIP_MEMORY_SCOPE_AGENT);
        }
    } else {
        // ================= ROLE C : layer-2 =================
        unsigned wr2[32];    // rk2 bf16-packed
        unsigned wk2[32];    // k2  bf16-packed
        if (c < 48) {
            const float* rb = rk2 + (size_t)(j * 64) * NCOL + col;
            const float* kb = k2  + (size_t)(j * 64) * NCOL + col;
            #pragma unroll
            for (int m = 0; m < 32; ++m) {
                wr2[m] = f2bfu(rb[(size_t)(2 * m) * NCOL])
                       | (f2bfu(rb[(size_t)(2 * m + 1) * NCOL]) << 16);
                wk2[m] = f2bfu(kb[(size_t)(2 * m) * NCOL])
                       | (f2bfu(kb[(size_t)(2 * m + 1) * NCOL]) << 16);
            }
        }
        float binz = 0, binr = 0, binh = 0, brz = 0, brr = 0, brh = 0;
        if (tid < 64) {
            int iu = tid & 15;
            binz = b2[u0 + iu]; binr = b2[UU + u0 + iu]; binh = b2[2 * UU + u0 + iu];
            brz = b2[NCOL + u0 + iu]; brr = b2[NCOL + UU + u0 + iu];
            brh = b2[NCOL + 2 * UU + u0 + iu];
        }
        __syncthreads();

        for (int t = 0; t < TSEQ; ++t) {
            if (tid < 64) {
                const int* fp = (tid < 32) ? &cflags[g * GB + tid]
                                           : &aflags[g * GB + (tid - 32)];
                const int thr = (tid < 32) ? t : (t + 1);
                while (!__all(__hip_atomic_load(fp, __ATOMIC_RELAXED,
                              __HIP_MEMORY_SCOPE_AGENT) >= thr)) {}
            }
            __syncthreads();
            {   // stage h1[t] (ring) and h2[t-1] (pingpong)
                const float* hs1 = h1ring + (size_t)(t & 7) * BB * UU;
                const float* hs2 = hp2 + (size_t)((t + 1) & 1) * BB * UU;
                #pragma unroll
                for (int i = 0; i < 4; ++i) {
                    int idx = i * 512 + tid;
                    int row = idx >> 9, k = idx & 511;
                    hl1[row][swz512(k)] = aload(&hs1[(size_t)(b0 + row) * UU + k]);
                    float v = (t == 0) ? h0[(size_t)(b0 + row) * UU + k]
                                       : aload(&hs2[(size_t)(b0 + row) * UU + k]);
                    hl2[row][swz512(k)] = v;
                }
            }
            __syncthreads();

            if (c < 48) {
                const int kb = j * 64;
                // ---- R-pass: recurrent GEMV on h2 ----
                float a0 = 0, a1 = 0, a2 = 0, a3 = 0;
                #pragma unroll
                for (int q0 = 0; q0 < 64; q0 += 4) {
                    int p = kb + (q0 ^ jsw);
                    float4 v0 = *(const float4*)&hl2[0][p];
                    float4 v1 = *(const float4*)&hl2[1][p];
                    float4 v2 = *(const float4*)&hl2[2][p];
                    float4 v3 = *(const float4*)&hl2[3][p];
                    unsigned wa = wr2[q0 >> 1], wb = wr2[(q0 >> 1) + 1];
                    float w0 = bflo(wa), w1 = bfhi(wa), w2 = bflo(wb), w3 = bfhi(wb);
                    a0 = fmaf(w0, v0.x, a0); a1 = fmaf(w0, v1.x, a1);
                    a2 = fmaf(w0, v2.x, a2); a3 = fmaf(w0, v3.x, a3);
                    a0 = fmaf(w1, v0.y, a0); a1 = fmaf(w1, v1.y, a1);
                    a2 = fmaf(w1, v2.y, a2); a3 = fmaf(w1, v3.y, a3);
                    a0 = fmaf(w2, v0.z, a0); a1 = fmaf(w2, v1.z, a1);
                    a2 = fmaf(w2, v2.z, a2); a3 = fmaf(w2, v3.z, a3);
                    a0 = fmaf(w3, v0.w, a0); a1 = fmaf(w3, v1.w, a1);
                    a2 = fmaf(w3, v2.w, a2); a3 = fmaf(w3, v3.w, a3);
                }
                // ---- X-pass: input GEMV on h1 ----
                float x0 = 0, x1 = 0, x2 = 0, x3 = 0;
                #pragma unroll
                for (int q0 = 0; q0 < 64; q0 += 4) {
                    int p = kb + (q0 ^ jsw);
                    float4 v0 = *(const float4*)&hl1[0][p];
                    float4 v1 = *(const float4*)&hl1[1][p];
                    float4 v2 = *(const float4*)&hl1[2][p];
                    float4 v3 = *(const float4*)&hl1[3][p];
                    unsigned wa = wk2[q0 >> 1], wb = wk2[(q0 >> 1) + 1];
                    float w0 = bflo(wa), w1 = bfhi(wa), w2 = bflo(wb), w3 = bfhi(wb);
                    x0 = fmaf(w0, v0.x, x0); x1 = fmaf(w0, v1.x, x1);
                    x2 = fmaf(w0, v2.x, x2); x3 = fmaf(w0, v3.x, x3);
                    x0 = fmaf(w1, v0.y, x0); x1 = fmaf(w1, v1.y, x1);
                    x2 = fmaf(w1, v2.y, x2); x3 = fmaf(w1, v3.y, x3);
                    x0 = fmaf(w2, v0.z, x0); x1 = fmaf(w2, v1.z, x1);
                    x2 = fmaf(w2, v2.z, x2); x3 = fmaf(w2, v3.z, x3);
                    x0 = fmaf(w3, v0.w, x0); x1 = fmaf(w3, v1.w, x1);
                    x2 = fmaf(w3, v2.w, x2); x3 = fmaf(w3, v3.w, x3);
                }
                #pragma unroll
                for (int m = 1; m < 8; m <<= 1) {
                    a0 += __shfl_xor(a0, m); a1 += __shfl_xor(a1, m);
                    a2 += __shfl_xor(a2, m); a3 += __shfl_xor(a3, m);
                    x0 += __shfl_xor(x0, m); x1 += __shfl_xor(x1, m);
                    x2 += __shfl_xor(x2, m); x3 += __shfl_xor(x3, m);
                }
                if (j == 0) {
                    innR[c][0] = a0; innR[c][1] = a1;
                    innR[c][2] = a2; innR[c][3] = a3;
                    innX[c][0] = x0; innX[c][1] = x1;
                    innX[c][2] = x2; innX[c][3] = x3;
                }
            }
            __syncthreads();

            if (tid < 64) {
                int bl = tid >> 4, iu = tid & 15, ug = u0 + iu;
                float rz = innR[iu][bl]      + brz;
                float rr = innR[16 + iu][bl] + brr;
                float rh = innR[32 + iu][bl] + brh;
                float xz = innX[iu][bl]      + binz;
                float xr = innX[16 + iu][bl] + binr;
                float xh = innX[32 + iu][bl] + binh;
                float z  = 1.f / (1.f + expf(-(xz + rz)));
                float r  = 1.f / (1.f + expf(-(xr + rr)));
                float hh = tanhf(xh + r * rh);
                float hold = hl2[bl][swz512(ug)];
                float hnew = z * hold + (1.f - z) * hh;
                astore(hp2 + (size_t)(t & 1) * BB * UU
                           + (size_t)(b0 + bl) * UU + ug, hnew);
                out2[((size_t)(b0 + bl) * TSEQ + t) * UU + ug] = hnew;
                if (t == TSEQ - 1) state2[(size_t)(b0 + bl) * UU + ug] = hnew;
            }
            __syncthreads();
            if (tid == 0)
                __hip_atomic_store(&cflags[g * GB + slot], t + 1,
                                   __ATOMIC_RELAXED, __HIP_MEMORY_SCOPE_AGENT);
        }
    }
}

// ---------------------------------------------------------------------------
extern "C" void kernel_launch(void* const* d_in, const int* in_sizes, int n_in,
                              void* d_out, int out_size, void* d_ws, size_t ws_size,
                              hipStream_t stream)
{
    const float* x      = (const float*)d_in[0];
    const float* hidden = (const float*)d_in[1];
    const float* k1     = (const float*)d_in[2];
    const float* rk1    = (const float*)d_in[3];
    const float* b1     = (const float*)d_in[4];
    const float* k2     = (const float*)d_in[5];
    const float* rk2    = (const float*)d_in[6];
    const float* b2     = (const float*)d_in[7];

    const int M = BB * TSEQ;                      // 65536
    const size_t XPROJ_ELEMS = (size_t)M * NCOL;

    float* xp1    = (float*)d_ws;                         // M*NCOL
    float* h1ring = xp1 + XPROJ_ELEMS;                    // RING*BB*UU
    float* hp2    = h1ring + (size_t)RING * BB * UU;      // 2*BB*UU
    int*   aflags = (int*)(hp2 + 2 * (size_t)BB * UU);
    int*   cflags = aflags + 256;

    size_t need = (XPROJ_ELEMS + (size_t)(RING + 2) * BB * UU) * sizeof(float)
                + 512 * sizeof(int);
    if (ws_size < need) return;

    float* out2   = (float*)d_out;
    float* state1 = out2 + (size_t)BB * TSEQ * UU;
    float* state2 = state1 + BB * UU;

    hipMemsetAsync(aflags, 0, 512 * sizeof(int), stream);

    dim3 ggrid(NCOL / 64, M / 64);
    gemm_bias<<<ggrid, 256, 0, stream>>>(x, k1, b1, xp1, M, NCOL, 256);

    gru_fused<<<512, 512, 0, stream>>>(xp1, hidden, rk1, b1, k2, rk2, b2,
                                       h1ring, hp2, aflags, cflags,
                                       out2, state1, state2);
}

// Round 7
// 50560.123 us; speedup vs baseline: 1.1956x; 1.1956x over previous
//
#include <hip/hip_runtime.h>
#include <hip/hip_bf16.h>
#include <cstdint>
#include <cstddef>

#define TSEQ 2048
#define BB   32
#define UU   512
#define NCOL 1536
#define GB   32      // blocks per group
#define RING 8       // h1 ring depth

static __device__ __forceinline__ float aload(const float* p) {
    return __int_as_float(__hip_atomic_load((const int*)p, __ATOMIC_RELAXED,
                                            __HIP_MEMORY_SCOPE_AGENT));
}
static __device__ __forceinline__ void astore(float* p, float v) {
    __hip_atomic_store((int*)p, __float_as_int(v), __ATOMIC_RELAXED,
                       __HIP_MEMORY_SCOPE_AGENT);
}
static __device__ __forceinline__ unsigned f2bfu(float f) {
    __hip_bfloat16 b = __float2bfloat16(f);
    unsigned short s;
    __builtin_memcpy(&s, &b, 2);
    return (unsigned)s;
}
static __device__ __forceinline__ float bflo(unsigned u) { return __uint_as_float(u << 16); }
static __device__ __forceinline__ float bfhi(unsigned u) { return __uint_as_float(u & 0xffff0000u); }
static __device__ __forceinline__ int swz512(int k) { return k ^ (((k >> 6) & 7) << 2); }

// ---------------------------------------------------------------------------
// fp32 GEMM for xp1 = x@k1 + b_in  (proven R3 kernel)
// ---------------------------------------------------------------------------
__global__ __launch_bounds__(256)
void gemm_bias(const float* __restrict__ A, const float* __restrict__ W,
               const float* __restrict__ bias, float* __restrict__ C,
               int M, int N, int K)
{
    __shared__ float As[16][68];
    __shared__ float Bs[16][64];

    const int tid = threadIdx.x;
    const int tx = tid & 15, ty = tid >> 4;
    const int m0 = blockIdx.y * 64, n0 = blockIdx.x * 64;

    float acc[4][4] = {};

    for (int k0 = 0; k0 < K; k0 += 16) {
        {
            int r  = tid >> 2;
            int kq = (tid & 3) * 4;
            float4 av = *(const float4*)&A[(size_t)(m0 + r) * K + k0 + kq];
            As[kq + 0][r] = av.x;
            As[kq + 1][r] = av.y;
            As[kq + 2][r] = av.z;
            As[kq + 3][r] = av.w;
        }
        {
            int kk = tid >> 4;
            int n  = (tid & 15) * 4;
            *(float4*)&Bs[kk][n] = *(const float4*)&W[(size_t)(k0 + kk) * N + n0 + n];
        }
        __syncthreads();

        #pragma unroll
        for (int kk = 0; kk < 16; ++kk) {
            float av0 = As[kk][ty * 4 + 0];
            float av1 = As[kk][ty * 4 + 1];
            float av2 = As[kk][ty * 4 + 2];
            float av3 = As[kk][ty * 4 + 3];
            float4 bv = *(const float4*)&Bs[kk][tx * 4];
            acc[0][0] = fmaf(av0, bv.x, acc[0][0]);
            acc[0][1] = fmaf(av0, bv.y, acc[0][1]);
            acc[0][2] = fmaf(av0, bv.z, acc[0][2]);
            acc[0][3] = fmaf(av0, bv.w, acc[0][3]);
            acc[1][0] = fmaf(av1, bv.x, acc[1][0]);
            acc[1][1] = fmaf(av1, bv.y, acc[1][1]);
            acc[1][2] = fmaf(av1, bv.z, acc[1][2]);
            acc[1][3] = fmaf(av1, bv.w, acc[1][3]);
            acc[2][0] = fmaf(av2, bv.x, acc[2][0]);
            acc[2][1] = fmaf(av2, bv.y, acc[2][1]);
            acc[2][2] = fmaf(av2, bv.z, acc[2][2]);
            acc[2][3] = fmaf(av2, bv.w, acc[2][3]);
            acc[3][0] = fmaf(av3, bv.x, acc[3][0]);
            acc[3][1] = fmaf(av3, bv.y, acc[3][1]);
            acc[3][2] = fmaf(av3, bv.z, acc[3][2]);
            acc[3][3] = fmaf(av3, bv.w, acc[3][3]);
        }
        __syncthreads();
    }

    float4 bb = *(const float4*)&bias[n0 + tx * 4];
    #pragma unroll
    for (int i = 0; i < 4; ++i) {
        float4 v;
        v.x = acc[i][0] + bb.x;
        v.y = acc[i][1] + bb.y;
        v.z = acc[i][2] + bb.z;
        v.w = acc[i][3] + bb.w;
        *(float4*)&C[(size_t)(m0 + ty * 4 + i) * N + n0 + tx * 4] = v;
    }
}

// ---------------------------------------------------------------------------
// Fused 2-layer GRU, one 1024-thread block per (group,slot): tid<512 = role A
// (layer 1, step i), tid>=512 = role C (layer 2, step i-1). Grid = 256 blocks
// = 1 block/CU -> co-residency unconditional (16 waves <= 32, 46KB LDS <= 64KB,
// __launch_bounds__(1024) forces VGPR <= 128 with no arg-2 ambiguity).
// hl1 (= h1[i-1]) is needed by BOTH halves -> staged once, shared.
// Cross-block exchange via RELAXED AGENT atomics (no fences); __syncthreads()
// drains vmcnt before flag posts. Deps per iteration i:
//   A@i  <- {group A @ i-1 (aflags>=i)}
//   C@i-1<- {group C @ i-2 (cflags>=i-1), group A @ i-1 (aflags>=i)}
// Group drift <= 1 iteration -> ring depth 8 is ample (no ring guard needed).
// ---------------------------------------------------------------------------
__global__ __launch_bounds__(1024)
void gru_fused(const float* __restrict__ xp1,  const float* __restrict__ h0,
               const float* __restrict__ rk1,  const float* __restrict__ b1,
               const float* __restrict__ k2,   const float* __restrict__ rk2,
               const float* __restrict__ b2,
               float* h1ring,                 // [RING][BB][UU]
               float* hp2,                    // [2][BB][UU]
               int* aflags, int* cflags,      // [256] each, zeroed
               float* __restrict__ out2, float* __restrict__ state1,
               float* __restrict__ state2)
{
    __shared__ float hl1[4][512];        // h1[i-1] (shared by A and C)
    __shared__ float hl2[4][512];        // h2[i-2] (C)
    __shared__ float xp[2][192];         // xp1 slices (A), dbuf
    __shared__ float innRA[48][4];
    __shared__ float innRC[48][4];
    __shared__ float innXC[48][4];
    __shared__ unsigned wl2[384 * 17];   // C: rk2 k=0..31, per-thread chunks

    const int tid  = threadIdx.x;
    const int lb   = blockIdx.x;               // 0..255
    const int g    = lb & 7, slot = lb >> 3;
    const int u0   = slot * 16, b0 = g * 4;
    const bool isA = (tid < 512);
    const int ht   = isA ? tid : (tid - 512);  // half-tid 0..511
    const int hc   = ht >> 3, hj = ht & 7;
    const int jsw  = hj << 2;
    const int col  = (hc < 48) ? ((hc >> 4) * UU + u0 + (hc & 15)) : 0;

    // ---- weights ----
    unsigned wMain[32];   // A: rk1 slice ; C: k2 slice (bf16-packed)
    unsigned wHi[16];     // C only: rk2 k=32..63
    if (hc < 48) {
        if (isA) {
            const float* rb = rk1 + (size_t)(hj * 64) * NCOL + col;
            #pragma unroll
            for (int m = 0; m < 32; ++m)
                wMain[m] = f2bfu(rb[(size_t)(2 * m) * NCOL])
                         | (f2bfu(rb[(size_t)(2 * m + 1) * NCOL]) << 16);
        } else {
            const float* rb = rk2 + (size_t)(hj * 64) * NCOL + col;
            const float* kb = k2  + (size_t)(hj * 64) * NCOL + col;
            #pragma unroll
            for (int m = 0; m < 32; ++m)
                wMain[m] = f2bfu(kb[(size_t)(2 * m) * NCOL])
                         | (f2bfu(kb[(size_t)(2 * m + 1) * NCOL]) << 16);
            const int wb = ht * 17;
            #pragma unroll
            for (int m = 0; m < 16; ++m) {
                wl2[wb + m] = f2bfu(rb[(size_t)(2 * m) * NCOL])
                            | (f2bfu(rb[(size_t)(2 * m + 1) * NCOL]) << 16);
                wHi[m] = f2bfu(rb[(size_t)(32 + 2 * m) * NCOL])
                       | (f2bfu(rb[(size_t)(33 + 2 * m) * NCOL]) << 16);
            }
        }
    }

    // ---- biases ----
    float bz = 0, brr = 0, bh = 0, b2z = 0, b2r = 0, b2h = 0;
    if (ht < 64) {
        int iu = ht & 15;
        if (isA) {
            bz  = b1[NCOL + u0 + iu];
            brr = b1[NCOL + UU + u0 + iu];
            bh  = b1[NCOL + 2 * UU + u0 + iu];
        } else {
            bz  = b2[NCOL + u0 + iu];
            brr = b2[NCOL + UU + u0 + iu];
            bh  = b2[NCOL + 2 * UU + u0 + iu];
            b2z = b2[u0 + iu];
            b2r = b2[UU + u0 + iu];
            b2h = b2[2 * UU + u0 + iu];
        }
    }

    // ---- prefill xp[0] with t=0 slice (A threads 384..511) ----
    if (isA && ht >= 384) {
        int p = ht - 384;
        {
            int cc = p >> 2, b = p & 3;
            xp[0][p] = xp1[((size_t)(b0 + b) * TSEQ + 0) * NCOL
                           + (cc >> 4) * UU + u0 + (cc & 15)];
        }
        int p2 = p + 128;
        if (p2 < 192) {
            int cc = p2 >> 2, b = p2 & 3;
            xp[0][p2] = xp1[((size_t)(b0 + b) * TSEQ + 0) * NCOL
                            + (cc >> 4) * UU + u0 + (cc & 15)];
        }
    }
    __syncthreads();

    for (int i = 0; i <= TSEQ; ++i) {
        // ---- poll phase ----
        if (i > 0) {
            if (isA) {
                if (ht < 64 && i < TSEQ) {
                    const int* fp = &aflags[g * GB + (ht & 31)];
                    while (!__all(__hip_atomic_load(fp, __ATOMIC_RELAXED,
                                  __HIP_MEMORY_SCOPE_AGENT) >= i)) {}
                }
            } else if (ht < 64) {
                const int thr = (ht < 32) ? (i - 1) : i;
                const int* fp = (ht < 32) ? &cflags[g * GB + ht]
                                          : &aflags[g * GB + (ht - 32)];
                while (!__all(__hip_atomic_load(fp, __ATOMIC_RELAXED,
                              __HIP_MEMORY_SCOPE_AGENT) >= thr)) {}
            }
        }
        __syncthreads();

        // ---- stage hl1 <- h1[i-1] (h0 at i==0); all 1024 threads ----
        {
            const float* hs = (i == 0) ? h0
                            : (h1ring + (size_t)((i - 1) & 7) * BB * UU);
            #pragma unroll
            for (int q = 0; q < 2; ++q) {
                int idx = q * 1024 + tid;
                int row = idx >> 9, k = idx & 511;
                float v = (i == 0) ? hs[(size_t)(b0 + row) * UU + k]
                                   : aload(&hs[(size_t)(b0 + row) * UU + k]);
                hl1[row][swz512(k)] = v;
            }
        }
        // ---- stage hl2 <- h2[i-2] (h0 at i==1); C half ----
        if (!isA && i >= 1) {
            const float* hs2 = hp2 + (size_t)(i & 1) * BB * UU;
            #pragma unroll
            for (int q = 0; q < 4; ++q) {
                int idx = q * 512 + ht;
                int row = idx >> 9, k = idx & 511;
                float v = (i == 1) ? h0[(size_t)(b0 + row) * UU + k]
                                   : aload(&hs2[(size_t)(b0 + row) * UU + k]);
                hl2[row][swz512(k)] = v;
            }
        }
        __syncthreads();

        // ---- work phase ----
        if (isA) {
            if (i < TSEQ) {
                if (hc < 48) {
                    float a0 = 0, a1 = 0, a2 = 0, a3 = 0;
                    const int kb = hj * 64;
                    #pragma unroll
                    for (int q0 = 0; q0 < 64; q0 += 4) {
                        int p = kb + (q0 ^ jsw);
                        float4 v0 = *(const float4*)&hl1[0][p];
                        float4 v1 = *(const float4*)&hl1[1][p];
                        float4 v2 = *(const float4*)&hl1[2][p];
                        float4 v3 = *(const float4*)&hl1[3][p];
                        unsigned wa = wMain[q0 >> 1], wb = wMain[(q0 >> 1) + 1];
                        float w0 = bflo(wa), w1 = bfhi(wa), w2 = bflo(wb), w3 = bfhi(wb);
                        a0 = fmaf(w0, v0.x, a0); a1 = fmaf(w0, v1.x, a1);
                        a2 = fmaf(w0, v2.x, a2); a3 = fmaf(w0, v3.x, a3);
                        a0 = fmaf(w1, v0.y, a0); a1 = fmaf(w1, v1.y, a1);
                        a2 = fmaf(w1, v2.y, a2); a3 = fmaf(w1, v3.y, a3);
                        a0 = fmaf(w2, v0.z, a0); a1 = fmaf(w2, v1.z, a1);
                        a2 = fmaf(w2, v2.z, a2); a3 = fmaf(w2, v3.z, a3);
                        a0 = fmaf(w3, v0.w, a0); a1 = fmaf(w3, v1.w, a1);
                        a2 = fmaf(w3, v2.w, a2); a3 = fmaf(w3, v3.w, a3);
                    }
                    #pragma unroll
                    for (int m = 1; m < 8; m <<= 1) {
                        a0 += __shfl_xor(a0, m); a1 += __shfl_xor(a1, m);
                        a2 += __shfl_xor(a2, m); a3 += __shfl_xor(a3, m);
                    }
                    if (hj == 0) {
                        innRA[hc][0] = a0; innRA[hc][1] = a1;
                        innRA[hc][2] = a2; innRA[hc][3] = a3;
                    }
                } else if (ht >= 384 && i + 1 < TSEQ) {   // prefetch xp1[i+1]
                    int p = ht - 384, nb = (i + 1) & 1;
                    {
                        int cc = p >> 2, b = p & 3;
                        xp[nb][p] = xp1[((size_t)(b0 + b) * TSEQ + (i + 1)) * NCOL
                                        + (cc >> 4) * UU + u0 + (cc & 15)];
                    }
                    int p2 = p + 128;
                    if (p2 < 192) {
                        int cc = p2 >> 2, b = p2 & 3;
                        xp[nb][p2] = xp1[((size_t)(b0 + b) * TSEQ + (i + 1)) * NCOL
                                         + (cc >> 4) * UU + u0 + (cc & 15)];
                    }
                }
            }
        } else if (i >= 1 && hc < 48) {
            const int kb = hj * 64;
            const int wb = ht * 17;
            // R-pass: rk2 (LDS low / regs high) x h2
            float a0 = 0, a1 = 0, a2 = 0, a3 = 0;
            #pragma unroll
            for (int q0 = 0; q0 < 64; q0 += 4) {
                int p = kb + (q0 ^ jsw);
                float4 v0 = *(const float4*)&hl2[0][p];
                float4 v1 = *(const float4*)&hl2[1][p];
                float4 v2 = *(const float4*)&hl2[2][p];
                float4 v3 = *(const float4*)&hl2[3][p];
                unsigned wa, wbb;
                if (q0 < 32) {
                    wa  = wl2[wb + (q0 >> 1)];
                    wbb = wl2[wb + (q0 >> 1) + 1];
                } else {
                    wa  = wHi[(q0 - 32) >> 1];
                    wbb = wHi[((q0 - 32) >> 1) + 1];
                }
                float w0 = bflo(wa), w1 = bfhi(wa), w2 = bflo(wbb), w3 = bfhi(wbb);
                a0 = fmaf(w0, v0.x, a0); a1 = fmaf(w0, v1.x, a1);
                a2 = fmaf(w0, v2.x, a2); a3 = fmaf(w0, v3.x, a3);
                a0 = fmaf(w1, v0.y, a0); a1 = fmaf(w1, v1.y, a1);
                a2 = fmaf(w1, v2.y, a2); a3 = fmaf(w1, v3.y, a3);
                a0 = fmaf(w2, v0.z, a0); a1 = fmaf(w2, v1.z, a1);
                a2 = fmaf(w2, v2.z, a2); a3 = fmaf(w2, v3.z, a3);
                a0 = fmaf(w3, v0.w, a0); a1 = fmaf(w3, v1.w, a1);
                a2 = fmaf(w3, v2.w, a2); a3 = fmaf(w3, v3.w, a3);
            }
            // X-pass: k2 (regs) x h1
            float x0 = 0, x1 = 0, x2 = 0, x3 = 0;
            #pragma unroll
            for (int q0 = 0; q0 < 64; q0 += 4) {
                int p = kb + (q0 ^ jsw);
                float4 v0 = *(const float4*)&hl1[0][p];
                float4 v1 = *(const float4*)&hl1[1][p];
                float4 v2 = *(const float4*)&hl1[2][p];
                float4 v3 = *(const float4*)&hl1[3][p];
                unsigned wa = wMain[q0 >> 1], wbb = wMain[(q0 >> 1) + 1];
                float w0 = bflo(wa), w1 = bfhi(wa), w2 = bflo(wbb), w3 = bfhi(wbb);
                x0 = fmaf(w0, v0.x, x0); x1 = fmaf(w0, v1.x, x1);
                x2 = fmaf(w0, v2.x, x2); x3 = fmaf(w0, v3.x, x3);
                x0 = fmaf(w1, v0.y, x0); x1 = fmaf(w1, v1.y, x1);
                x2 = fmaf(w1, v2.y, x2); x3 = fmaf(w1, v3.y, x3);
                x0 = fmaf(w2, v0.z, x0); x1 = fmaf(w2, v1.z, x1);
                x2 = fmaf(w2, v2.z, x2); x3 = fmaf(w2, v3.z, x3);
                x0 = fmaf(w3, v0.w, x0); x1 = fmaf(w3, v1.w, x1);
                x2 = fmaf(w3, v2.w, x2); x3 = fmaf(w3, v3.w, x3);
            }
            #pragma unroll
            for (int m = 1; m < 8; m <<= 1) {
                a0 += __shfl_xor(a0, m); a1 += __shfl_xor(a1, m);
                a2 += __shfl_xor(a2, m); a3 += __shfl_xor(a3, m);
                x0 += __shfl_xor(x0, m); x1 += __shfl_xor(x1, m);
                x2 += __shfl_xor(x2, m); x3 += __shfl_xor(x3, m);
            }
            if (hj == 0) {
                innRC[hc][0] = a0; innRC[hc][1] = a1;
                innRC[hc][2] = a2; innRC[hc][3] = a3;
                innXC[hc][0] = x0; innXC[hc][1] = x1;
                innXC[hc][2] = x2; innXC[hc][3] = x3;
            }
        }
        __syncthreads();

        // ---- gates ----
        if (isA) {
            if (i < TSEQ && ht < 64) {
                int bl = ht >> 4, iu = ht & 15, ug = u0 + iu;
                float rz = innRA[iu][bl]      + bz;
                float rr = innRA[16 + iu][bl] + brr;
                float rh = innRA[32 + iu][bl] + bh;
                const float* xv = xp[i & 1];
                float xz = xv[iu * 4 + bl];
                float xr = xv[(16 + iu) * 4 + bl];
                float xh = xv[(32 + iu) * 4 + bl];
                float z  = 1.f / (1.f + expf(-(xz + rz)));
                float r  = 1.f / (1.f + expf(-(xr + rr)));
                float hh = tanhf(xh + r * rh);
                float hold = hl1[bl][swz512(ug)];
                float hnew = z * hold + (1.f - z) * hh;
                astore(h1ring + (size_t)(i & 7) * BB * UU
                              + (size_t)(b0 + bl) * UU + ug, hnew);
                if (i == TSEQ - 1) state1[(size_t)(b0 + bl) * UU + ug] = hnew;
            }
        } else if (i >= 1 && ht < 64) {
            int tc = i - 1;
            int bl = ht >> 4, iu = ht & 15, ug = u0 + iu;
            float rz = innRC[iu][bl]      + bz;
            float rr = innRC[16 + iu][bl] + brr;
            float rh = innRC[32 + iu][bl] + bh;
            float xz = innXC[iu][bl]      + b2z;
            float xr = innXC[16 + iu][bl] + b2r;
            float xh = innXC[32 + iu][bl] + b2h;
            float z  = 1.f / (1.f + expf(-(xz + rz)));
            float r  = 1.f / (1.f + expf(-(xr + rr)));
            float hh = tanhf(xh + r * rh);
            float hold = hl2[bl][swz512(ug)];
            float hnew = z * hold + (1.f - z) * hh;
            astore(hp2 + (size_t)(tc & 1) * BB * UU
                       + (size_t)(b0 + bl) * UU + ug, hnew);
            out2[((size_t)(b0 + bl) * TSEQ + tc) * UU + ug] = hnew;
            if (tc == TSEQ - 1) state2[(size_t)(b0 + bl) * UU + ug] = hnew;
        }
        __syncthreads();   // drains vmcnt: all h stores at MALL before flags

        if (tid == 0 && i < TSEQ)
            __hip_atomic_store(&aflags[g * GB + slot], i + 1,
                               __ATOMIC_RELAXED, __HIP_MEMORY_SCOPE_AGENT);
        if (tid == 512 && i >= 1)
            __hip_atomic_store(&cflags[g * GB + slot], i,
                               __ATOMIC_RELAXED, __HIP_MEMORY_SCOPE_AGENT);
    }
}

// ---------------------------------------------------------------------------
extern "C" void kernel_launch(void* const* d_in, const int* in_sizes, int n_in,
                              void* d_out, int out_size, void* d_ws, size_t ws_size,
                              hipStream_t stream)
{
    const float* x      = (const float*)d_in[0];
    const float* hidden = (const float*)d_in[1];
    const float* k1     = (const float*)d_in[2];
    const float* rk1    = (const float*)d_in[3];
    const float* b1     = (const float*)d_in[4];
    const float* k2     = (const float*)d_in[5];
    const float* rk2    = (const float*)d_in[6];
    const float* b2     = (const float*)d_in[7];

    const int M = BB * TSEQ;                      // 65536
    const size_t XPROJ_ELEMS = (size_t)M * NCOL;

    float* xp1    = (float*)d_ws;                         // M*NCOL
    float* h1ring = xp1 + XPROJ_ELEMS;                    // RING*BB*UU
    float* hp2    = h1ring + (size_t)RING * BB * UU;      // 2*BB*UU
    int*   aflags = (int*)(hp2 + 2 * (size_t)BB * UU);
    int*   cflags = aflags + 256;

    size_t need = (XPROJ_ELEMS + (size_t)(RING + 2) * BB * UU) * sizeof(float)
                + 512 * sizeof(int);
    if (ws_size < need) return;

    float* out2   = (float*)d_out;
    float* state1 = out2 + (size_t)BB * TSEQ * UU;
    float* state2 = state1 + BB * UU;

    hipMemsetAsync(aflags, 0, 512 * sizeof(int), stream);

    dim3 ggrid(NCOL / 64, M / 64);
    gemm_bias<<<ggrid, 256, 0, stream>>>(x, k1, b1, xp1, M, NCOL, 256);

    gru_fused<<<256, 1024, 0, stream>>>(xp1, hidden, rk1, b1, k2, rk2, b2,
                                        h1ring, hp2, aflags, cflags,
                                        out2, state1, state2);
}

// Round 8
// 47408.344 us; speedup vs baseline: 1.2751x; 1.0665x over previous
//
#include <hip/hip_runtime.h>
#include <hip/hip_bf16.h>
#include <cstdint>
#include <cstddef>

#define TSEQ 2048
#define BB   32
#define UU   512
#define NCOL 1536
#define GB   32      // blocks per group
#define RING 8       // h1 ring depth

static __device__ __forceinline__ float aload(const float* p) {
    return __int_as_float(__hip_atomic_load((const int*)p, __ATOMIC_RELAXED,
                                            __HIP_MEMORY_SCOPE_AGENT));
}
static __device__ __forceinline__ void astore(float* p, float v) {
    __hip_atomic_store((int*)p, __float_as_int(v), __ATOMIC_RELAXED,
                       __HIP_MEMORY_SCOPE_AGENT);
}
static __device__ __forceinline__ unsigned f2bfu(float f) {
    __hip_bfloat16 b = __float2bfloat16(f);
    unsigned short s;
    __builtin_memcpy(&s, &b, 2);
    return (unsigned)s;
}
static __device__ __forceinline__ float bflo(unsigned u) { return __uint_as_float(u << 16); }
static __device__ __forceinline__ float bfhi(unsigned u) { return __uint_as_float(u & 0xffff0000u); }
static __device__ __forceinline__ int swz512(int k) { return k ^ (((k >> 6) & 7) << 2); }

// ---------------------------------------------------------------------------
// fp32 GEMM for xp1 = x@k1 + b_in  (proven R3 kernel)
// ---------------------------------------------------------------------------
__global__ __launch_bounds__(256)
void gemm_bias(const float* __restrict__ A, const float* __restrict__ W,
               const float* __restrict__ bias, float* __restrict__ C,
               int M, int N, int K)
{
    __shared__ float As[16][68];
    __shared__ float Bs[16][64];

    const int tid = threadIdx.x;
    const int tx = tid & 15, ty = tid >> 4;
    const int m0 = blockIdx.y * 64, n0 = blockIdx.x * 64;

    float acc[4][4] = {};

    for (int k0 = 0; k0 < K; k0 += 16) {
        {
            int r  = tid >> 2;
            int kq = (tid & 3) * 4;
            float4 av = *(const float4*)&A[(size_t)(m0 + r) * K + k0 + kq];
            As[kq + 0][r] = av.x;
            As[kq + 1][r] = av.y;
            As[kq + 2][r] = av.z;
            As[kq + 3][r] = av.w;
        }
        {
            int kk = tid >> 4;
            int n  = (tid & 15) * 4;
            *(float4*)&Bs[kk][n] = *(const float4*)&W[(size_t)(k0 + kk) * N + n0 + n];
        }
        __syncthreads();

        #pragma unroll
        for (int kk = 0; kk < 16; ++kk) {
            float av0 = As[kk][ty * 4 + 0];
            float av1 = As[kk][ty * 4 + 1];
            float av2 = As[kk][ty * 4 + 2];
            float av3 = As[kk][ty * 4 + 3];
            float4 bv = *(const float4*)&Bs[kk][tx * 4];
            acc[0][0] = fmaf(av0, bv.x, acc[0][0]);
            acc[0][1] = fmaf(av0, bv.y, acc[0][1]);
            acc[0][2] = fmaf(av0, bv.z, acc[0][2]);
            acc[0][3] = fmaf(av0, bv.w, acc[0][3]);
            acc[1][0] = fmaf(av1, bv.x, acc[1][0]);
            acc[1][1] = fmaf(av1, bv.y, acc[1][1]);
            acc[1][2] = fmaf(av1, bv.z, acc[1][2]);
            acc[1][3] = fmaf(av1, bv.w, acc[1][3]);
            acc[2][0] = fmaf(av2, bv.x, acc[2][0]);
            acc[2][1] = fmaf(av2, bv.y, acc[2][1]);
            acc[2][2] = fmaf(av2, bv.z, acc[2][2]);
            acc[2][3] = fmaf(av2, bv.w, acc[2][3]);
            acc[3][0] = fmaf(av3, bv.x, acc[3][0]);
            acc[3][1] = fmaf(av3, bv.y, acc[3][1]);
            acc[3][2] = fmaf(av3, bv.z, acc[3][2]);
            acc[3][3] = fmaf(av3, bv.w, acc[3][3]);
        }
        __syncthreads();
    }

    float4 bb = *(const float4*)&bias[n0 + tx * 4];
    #pragma unroll
    for (int i = 0; i < 4; ++i) {
        float4 v;
        v.x = acc[i][0] + bb.x;
        v.y = acc[i][1] + bb.y;
        v.z = acc[i][2] + bb.z;
        v.w = acc[i][3] + bb.w;
        *(float4*)&C[(size_t)(m0 + ty * 4 + i) * N + n0 + tx * 4] = v;
    }
}

// ---------------------------------------------------------------------------
// Fused 2-layer GRU, one 1024-thread block per (group,slot): tid<512 = role A
// (layer 1, step i), tid>=512 = role C (layer 2, step i-1). Grid = 256 blocks
// = 1 block/CU.
// amdgpu_waves_per_eu(4,4): pins the register allocator's occupancy window to
// exactly what this kernel occupies (16 waves/CU = 4/EU) -> 128-VGPR budget,
// no occupancy-chasing spill. (R4/R5/R7 evidence: without the max bound, the
// allocator targets 8 waves/EU -> 64-VGPR cap -> weight arrays spill to
// scratch -> ~100 GB FETCH.)
// Cross-block exchange via RELAXED AGENT atomics (no fences); __syncthreads()
// drains vmcnt before flag posts. Deps per iteration i:
//   A@i  <- {group A @ i-1 (aflags>=i)}
//   C@i-1<- {group C @ i-2 (cflags>=i-1), group A @ i-1 (aflags>=i)}
// Group drift <= 1 iteration -> ring depth 8 is ample.
// ---------------------------------------------------------------------------
__global__ __attribute__((amdgpu_waves_per_eu(4, 4))) __launch_bounds__(1024)
void gru_fused(const float* __restrict__ xp1,  const float* __restrict__ h0,
               const float* __restrict__ rk1,  const float* __restrict__ b1,
               const float* __restrict__ k2,   const float* __restrict__ rk2,
               const float* __restrict__ b2,
               float* h1ring,                 // [RING][BB][UU]
               float* hp2,                    // [2][BB][UU]
               int* aflags, int* cflags,      // [256] each, zeroed
               float* __restrict__ out2, float* __restrict__ state1,
               float* __restrict__ state2)
{
    __shared__ float hl1[4][512];        // h1[i-1] (shared by A and C)
    __shared__ float hl2[4][512];        // h2[i-2] (C)
    __shared__ float xp[2][192];         // xp1 slices (A), dbuf
    __shared__ float innRA[48][4];
    __shared__ float innRC[48][4];
    __shared__ float innXC[48][4];
    __shared__ unsigned wl2[384 * 17];   // C: rk2 k=0..31, per-thread chunks

    const int tid  = threadIdx.x;
    const int lb   = blockIdx.x;               // 0..255
    const int g    = lb & 7, slot = lb >> 3;
    const int u0   = slot * 16, b0 = g * 4;
    const bool isA = (tid < 512);
    const int ht   = isA ? tid : (tid - 512);  // half-tid 0..511
    const int hc   = ht >> 3, hj = ht & 7;
    const int jsw  = hj << 2;
    const int col  = (hc < 48) ? ((hc >> 4) * UU + u0 + (hc & 15)) : 0;

    // ---- weights ----
    unsigned wMain[32];   // A: rk1 slice ; C: k2 slice (bf16-packed)
    unsigned wHi[16];     // C only: rk2 k=32..63
    if (hc < 48) {
        if (isA) {
            const float* rb = rk1 + (size_t)(hj * 64) * NCOL + col;
            #pragma unroll
            for (int m = 0; m < 32; ++m)
                wMain[m] = f2bfu(rb[(size_t)(2 * m) * NCOL])
                         | (f2bfu(rb[(size_t)(2 * m + 1) * NCOL]) << 16);
        } else {
            const float* rb = rk2 + (size_t)(hj * 64) * NCOL + col;
            const float* kb = k2  + (size_t)(hj * 64) * NCOL + col;
            #pragma unroll
            for (int m = 0; m < 32; ++m)
                wMain[m] = f2bfu(kb[(size_t)(2 * m) * NCOL])
                         | (f2bfu(kb[(size_t)(2 * m + 1) * NCOL]) << 16);
            const int wb = ht * 17;
            #pragma unroll
            for (int m = 0; m < 16; ++m) {
                wl2[wb + m] = f2bfu(rb[(size_t)(2 * m) * NCOL])
                            | (f2bfu(rb[(size_t)(2 * m + 1) * NCOL]) << 16);
                wHi[m] = f2bfu(rb[(size_t)(32 + 2 * m) * NCOL])
                       | (f2bfu(rb[(size_t)(33 + 2 * m) * NCOL]) << 16);
            }
        }
    }

    // ---- biases ----
    float bz = 0, brr = 0, bh = 0, b2z = 0, b2r = 0, b2h = 0;
    if (ht < 64) {
        int iu = ht & 15;
        if (isA) {
            bz  = b1[NCOL + u0 + iu];
            brr = b1[NCOL + UU + u0 + iu];
            bh  = b1[NCOL + 2 * UU + u0 + iu];
        } else {
            bz  = b2[NCOL + u0 + iu];
            brr = b2[NCOL + UU + u0 + iu];
            bh  = b2[NCOL + 2 * UU + u0 + iu];
            b2z = b2[u0 + iu];
            b2r = b2[UU + u0 + iu];
            b2h = b2[2 * UU + u0 + iu];
        }
    }

    // ---- prefill xp[0] with t=0 slice (A threads 384..511) ----
    if (isA && ht >= 384) {
        int p = ht - 384;
        {
            int cc = p >> 2, b = p & 3;
            xp[0][p] = xp1[((size_t)(b0 + b) * TSEQ + 0) * NCOL
                           + (cc >> 4) * UU + u0 + (cc & 15)];
        }
        int p2 = p + 128;
        if (p2 < 192) {
            int cc = p2 >> 2, b = p2 & 3;
            xp[0][p2] = xp1[((size_t)(b0 + b) * TSEQ + 0) * NCOL
                            + (cc >> 4) * UU + u0 + (cc & 15)];
        }
    }
    __syncthreads();

    for (int i = 0; i <= TSEQ; ++i) {
        // ---- poll phase ----
        if (i > 0) {
            if (isA) {
                if (ht < 64 && i < TSEQ) {
                    const int* fp = &aflags[g * GB + (ht & 31)];
                    while (!__all(__hip_atomic_load(fp, __ATOMIC_RELAXED,
                                  __HIP_MEMORY_SCOPE_AGENT) >= i)) {}
                }
            } else if (ht < 64) {
                const int thr = (ht < 32) ? (i - 1) : i;
                const int* fp = (ht < 32) ? &cflags[g * GB + ht]
                                          : &aflags[g * GB + (ht - 32)];
                while (!__all(__hip_atomic_load(fp, __ATOMIC_RELAXED,
                              __HIP_MEMORY_SCOPE_AGENT) >= thr)) {}
            }
        }
        __syncthreads();

        // ---- stage hl1 <- h1[i-1] (h0 at i==0); all 1024 threads ----
        {
            const float* hs = (i == 0) ? h0
                            : (h1ring + (size_t)((i - 1) & 7) * BB * UU);
            #pragma unroll
            for (int q = 0; q < 2; ++q) {
                int idx = q * 1024 + tid;
                int row = idx >> 9, k = idx & 511;
                float v = (i == 0) ? hs[(size_t)(b0 + row) * UU + k]
                                   : aload(&hs[(size_t)(b0 + row) * UU + k]);
                hl1[row][swz512(k)] = v;
            }
        }
        // ---- stage hl2 <- h2[i-2] (h0 at i==1); C half ----
        if (!isA && i >= 1) {
            const float* hs2 = hp2 + (size_t)(i & 1) * BB * UU;
            #pragma unroll
            for (int q = 0; q < 4; ++q) {
                int idx = q * 512 + ht;
                int row = idx >> 9, k = idx & 511;
                float v = (i == 1) ? h0[(size_t)(b0 + row) * UU + k]
                                   : aload(&hs2[(size_t)(b0 + row) * UU + k]);
                hl2[row][swz512(k)] = v;
            }
        }
        __syncthreads();

        // ---- work phase ----
        if (isA) {
            if (i < TSEQ) {
                if (hc < 48) {
                    float a0 = 0, a1 = 0, a2 = 0, a3 = 0;
                    const int kb = hj * 64;
                    #pragma unroll
                    for (int q0 = 0; q0 < 64; q0 += 4) {
                        int p = kb + (q0 ^ jsw);
                        float4 v0 = *(const float4*)&hl1[0][p];
                        float4 v1 = *(const float4*)&hl1[1][p];
                        float4 v2 = *(const float4*)&hl1[2][p];
                        float4 v3 = *(const float4*)&hl1[3][p];
                        unsigned wa = wMain[q0 >> 1], wb = wMain[(q0 >> 1) + 1];
                        float w0 = bflo(wa), w1 = bfhi(wa), w2 = bflo(wb), w3 = bfhi(wb);
                        a0 = fmaf(w0, v0.x, a0); a1 = fmaf(w0, v1.x, a1);
                        a2 = fmaf(w0, v2.x, a2); a3 = fmaf(w0, v3.x, a3);
                        a0 = fmaf(w1, v0.y, a0); a1 = fmaf(w1, v1.y, a1);
                        a2 = fmaf(w1, v2.y, a2); a3 = fmaf(w1, v3.y, a3);
                        a0 = fmaf(w2, v0.z, a0); a1 = fmaf(w2, v1.z, a1);
                        a2 = fmaf(w2, v2.z, a2); a3 = fmaf(w2, v3.z, a3);
                        a0 = fmaf(w3, v0.w, a0); a1 = fmaf(w3, v1.w, a1);
                        a2 = fmaf(w3, v2.w, a2); a3 = fmaf(w3, v3.w, a3);
                    }
                    #pragma unroll
                    for (int m = 1; m < 8; m <<= 1) {
                        a0 += __shfl_xor(a0, m); a1 += __shfl_xor(a1, m);
                        a2 += __shfl_xor(a2, m); a3 += __shfl_xor(a3, m);
                    }
                    if (hj == 0) {
                        innRA[hc][0] = a0; innRA[hc][1] = a1;
                        innRA[hc][2] = a2; innRA[hc][3] = a3;
                    }
                } else if (ht >= 384 && i + 1 < TSEQ) {   // prefetch xp1[i+1]
                    int p = ht - 384, nb = (i + 1) & 1;
                    {
                        int cc = p >> 2, b = p & 3;
                        xp[nb][p] = xp1[((size_t)(b0 + b) * TSEQ + (i + 1)) * NCOL
                                        + (cc >> 4) * UU + u0 + (cc & 15)];
                    }
                    int p2 = p + 128;
                    if (p2 < 192) {
                        int cc = p2 >> 2, b = p2 & 3;
                        xp[nb][p2] = xp1[((size_t)(b0 + b) * TSEQ + (i + 1)) * NCOL
                                         + (cc >> 4) * UU + u0 + (cc & 15)];
                    }
                }
            }
        } else if (i >= 1 && hc < 48) {
            const int kb = hj * 64;
            const int wb = ht * 17;
            // R-pass: rk2 (LDS low / regs high) x h2
            float a0 = 0, a1 = 0, a2 = 0, a3 = 0;
            #pragma unroll
            for (int q0 = 0; q0 < 64; q0 += 4) {
                int p = kb + (q0 ^ jsw);
                float4 v0 = *(const float4*)&hl2[0][p];
                float4 v1 = *(const float4*)&hl2[1][p];
                float4 v2 = *(const float4*)&hl2[2][p];
                float4 v3 = *(const float4*)&hl2[3][p];
                unsigned wa, wbb;
                if (q0 < 32) {
                    wa  = wl2[wb + (q0 >> 1)];
                    wbb = wl2[wb + (q0 >> 1) + 1];
                } else {
                    wa  = wHi[(q0 - 32) >> 1];
                    wbb = wHi[((q0 - 32) >> 1) + 1];
                }
                float w0 = bflo(wa), w1 = bfhi(wa), w2 = bflo(wbb), w3 = bfhi(wbb);
                a0 = fmaf(w0, v0.x, a0); a1 = fmaf(w0, v1.x, a1);
                a2 = fmaf(w0, v2.x, a2); a3 = fmaf(w0, v3.x, a3);
                a0 = fmaf(w1, v0.y, a0); a1 = fmaf(w1, v1.y, a1);
                a2 = fmaf(w1, v2.y, a2); a3 = fmaf(w1, v3.y, a3);
                a0 = fmaf(w2, v0.z, a0); a1 = fmaf(w2, v1.z, a1);
                a2 = fmaf(w2, v2.z, a2); a3 = fmaf(w2, v3.z, a3);
                a0 = fmaf(w3, v0.w, a0); a1 = fmaf(w3, v1.w, a1);
                a2 = fmaf(w3, v2.w, a2); a3 = fmaf(w3, v3.w, a3);
            }
            // X-pass: k2 (regs) x h1
            float x0 = 0, x1 = 0, x2 = 0, x3 = 0;
            #pragma unroll
            for (int q0 = 0; q0 < 64; q0 += 4) {
                int p = kb + (q0 ^ jsw);
                float4 v0 = *(const float4*)&hl1[0][p];
                float4 v1 = *(const float4*)&hl1[1][p];
                float4 v2 = *(const float4*)&hl1[2][p];
                float4 v3 = *(const float4*)&hl1[3][p];
                unsigned wa = wMain[q0 >> 1], wbb = wMain[(q0 >> 1) + 1];
                float w0 = bflo(wa), w1 = bfhi(wa), w2 = bflo(wbb), w3 = bfhi(wbb);
                x0 = fmaf(w0, v0.x, x0); x1 = fmaf(w0, v1.x, x1);
                x2 = fmaf(w0, v2.x, x2); x3 = fmaf(w0, v3.x, x3);
                x0 = fmaf(w1, v0.y, x0); x1 = fmaf(w1, v1.y, x1);
                x2 = fmaf(w1, v2.y, x2); x3 = fmaf(w1, v3.y, x3);
                x0 = fmaf(w2, v0.z, x0); x1 = fmaf(w2, v1.z, x1);
                x2 = fmaf(w2, v2.z, x2); x3 = fmaf(w2, v3.z, x3);
                x0 = fmaf(w3, v0.w, x0); x1 = fmaf(w3, v1.w, x1);
                x2 = fmaf(w3, v2.w, x2); x3 = fmaf(w3, v3.w, x3);
            }
            #pragma unroll
            for (int m = 1; m < 8; m <<= 1) {
                a0 += __shfl_xor(a0, m); a1 += __shfl_xor(a1, m);
                a2 += __shfl_xor(a2, m); a3 += __shfl_xor(a3, m);
                x0 += __shfl_xor(x0, m); x1 += __shfl_xor(x1, m);
                x2 += __shfl_xor(x2, m); x3 += __shfl_xor(x3, m);
            }
            if (hj == 0) {
                innRC[hc][0] = a0; innRC[hc][1] = a1;
                innRC[hc][2] = a2; innRC[hc][3] = a3;
                innXC[hc][0] = x0; innXC[hc][1] = x1;
                innXC[hc][2] = x2; innXC[hc][3] = x3;
            }
        }
        __syncthreads();

        // ---- gates ----
        if (isA) {
            if (i < TSEQ && ht < 64) {
                int bl = ht >> 4, iu = ht & 15, ug = u0 + iu;
                float rz = innRA[iu][bl]      + bz;
                float rr = innRA[16 + iu][bl] + brr;
                float rh = innRA[32 + iu][bl] + bh;
                const float* xv = xp[i & 1];
                float xz = xv[iu * 4 + bl];
                float xr = xv[(16 + iu) * 4 + bl];
                float xh = xv[(32 + iu) * 4 + bl];
                float z  = 1.f / (1.f + expf(-(xz + rz)));
                float r  = 1.f / (1.f + expf(-(xr + rr)));
                float hh = tanhf(xh + r * rh);
                float hold = hl1[bl][swz512(ug)];
                float hnew = z * hold + (1.f - z) * hh;
                astore(h1ring + (size_t)(i & 7) * BB * UU
                              + (size_t)(b0 + bl) * UU + ug, hnew);
                if (i == TSEQ - 1) state1[(size_t)(b0 + bl) * UU + ug] = hnew;
            }
        } else if (i >= 1 && ht < 64) {
            int tc = i - 1;
            int bl = ht >> 4, iu = ht & 15, ug = u0 + iu;
            float rz = innRC[iu][bl]      + bz;
            float rr = innRC[16 + iu][bl] + brr;
            float rh = innRC[32 + iu][bl] + bh;
            float xz = innXC[iu][bl]      + b2z;
            float xr = innXC[16 + iu][bl] + b2r;
            float xh = innXC[32 + iu][bl] + b2h;
            float z  = 1.f / (1.f + expf(-(xz + rz)));
            float r  = 1.f / (1.f + expf(-(xr + rr)));
            float hh = tanhf(xh + r * rh);
            float hold = hl2[bl][swz512(ug)];
            float hnew = z * hold + (1.f - z) * hh;
            astore(hp2 + (size_t)(tc & 1) * BB * UU
                       + (size_t)(b0 + bl) * UU + ug, hnew);
            out2[((size_t)(b0 + bl) * TSEQ + tc) * UU + ug] = hnew;
            if (tc == TSEQ - 1) state2[(size_t)(b0 + bl) * UU + ug] = hnew;
        }
        __syncthreads();   // drains vmcnt: all h stores at MALL before flags

        if (tid == 0 && i < TSEQ)
            __hip_atomic_store(&aflags[g * GB + slot], i + 1,
                               __ATOMIC_RELAXED, __HIP_MEMORY_SCOPE_AGENT);
        if (tid == 512 && i >= 1)
            __hip_atomic_store(&cflags[g * GB + slot], i,
                               __ATOMIC_RELAXED, __HIP_MEMORY_SCOPE_AGENT);
    }
}

// ---------------------------------------------------------------------------
extern "C" void kernel_launch(void* const* d_in, const int* in_sizes, int n_in,
                              void* d_out, int out_size, void* d_ws, size_t ws_size,
                              hipStream_t stream)
{
    const float* x      = (const float*)d_in[0];
    const float* hidden = (const float*)d_in[1];
    const float* k1     = (const float*)d_in[2];
    const float* rk1    = (const float*)d_in[3];
    const float* b1     = (const float*)d_in[4];
    const float* k2     = (const float*)d_in[5];
    const float* rk2    = (const float*)d_in[6];
    const float* b2     = (const float*)d_in[7];

    const int M = BB * TSEQ;                      // 65536
    const size_t XPROJ_ELEMS = (size_t)M * NCOL;

    float* xp1    = (float*)d_ws;                         // M*NCOL
    float* h1ring = xp1 + XPROJ_ELEMS;                    // RING*BB*UU
    float* hp2    = h1ring + (size_t)RING * BB * UU;      // 2*BB*UU
    int*   aflags = (int*)(hp2 + 2 * (size_t)BB * UU);
    int*   cflags = aflags + 256;

    size_t need = (XPROJ_ELEMS + (size_t)(RING + 2) * BB * UU) * sizeof(float)
                + 512 * sizeof(int);
    if (ws_size < need) return;

    float* out2   = (float*)d_out;
    float* state1 = out2 + (size_t)BB * TSEQ * UU;
    float* state2 = state1 + BB * UU;

    hipMemsetAsync(aflags, 0, 512 * sizeof(int), stream);

    dim3 ggrid(NCOL / 64, M / 64);
    gemm_bias<<<ggrid, 256, 0, stream>>>(x, k1, b1, xp1, M, NCOL, 256);

    gru_fused<<<256, 1024, 0, stream>>>(xp1, hidden, rk1, b1, k2, rk2, b2,
                                        h1ring, hp2, aflags, cflags,
                                        out2, state1, state2);
}